// Round 4
// baseline (175.033 us; speedup 1.0000x reference)
//
#include <hip/hip_runtime.h>

// WeightedDiceLoss on MI355X -- fused single-pass, segment-sum window version.
// input, target: (64,1,512,512) fp32. Output: scalar fp32.
// weight = 1 + 5*|box31(target) - target|; loss = 1 - (2*I+1)/(A+B+1).
//
// One wave owns an 8-row band of one image, full 512-col width (8 cols/lane).
// Lane maintains 8 vertical running 31-sums; the 31-wide horizontal window for
// its 8 output columns is built from per-lane segment sums:
//   win[j] = S3 + suffix_{lane-2}[j+1] + prefix_{lane+2}[j]
// (16 shuffles/row, boundary zero-padding folded into mask fmas). No LDS for
// data; 4 waves/block, 4096 waves total -> 16 waves/CU for latency hiding.

#define BATCH 64
#define H     512
#define W     512
#define PADR  15
#define NSEG  64                 // row-bands per image
#define RB    (H / NSEG)         // 8 rows per band
#define NWAVE (BATCH * NSEG)     // 4096 waves
#define NBLK  (NWAVE / 4)        // 1024 blocks of 256 threads

__global__ __launch_bounds__(256) void fused_kernel(const float* __restrict__ tgt,
                                                    const float* __restrict__ inp,
                                                    float4* __restrict__ partials) {
    const int tid  = threadIdx.x;
    const int lane = tid & 63;
    const int wv   = tid >> 6;
    const int g    = blockIdx.x * 4 + wv;    // global wave id, 0..NWAVE-1
    const int band = g & (NSEG - 1);
    const int b    = g >> 6;                 // image index (NSEG==64)
    const int r0   = band * RB;
    const int col0 = lane * 8;
    const float* timg = tgt + (size_t)b * H * W;
    const float* iimg = inp + (size_t)b * H * W;

    // boundary masks (zero padding comes from zeroing cross-lane contributions)
    const float mL1 = (lane >= 1) ? 1.f : 0.f;
    const float mR1 = (lane <= 62) ? 1.f : 0.f;
    const float mL2 = (lane >= 2) ? 1.f : 0.f;
    const float mR2 = (lane <= 61) ? 1.f : 0.f;

    // vertical running sums vr[k] = sum_{r in [h-15,h+15]} tgt[r][col0+k]
    float vr[8];
    #pragma unroll
    for (int k = 0; k < 8; ++k) vr[k] = 0.f;
    #pragma unroll
    for (int j = -PADR; j <= PADR; ++j) {
        const int r = r0 + j;
        if (r >= 0 && r < H) {
            const float4 a = *(const float4*)(timg + (size_t)r * W + col0);
            const float4 c = *(const float4*)(timg + (size_t)r * W + col0 + 4);
            vr[0] += a.x; vr[1] += a.y; vr[2] += a.z; vr[3] += a.w;
            vr[4] += c.x; vr[5] += c.y; vr[6] += c.z; vr[7] += c.w;
        }
    }

    const float inv = 1.0f / 961.0f;
    float aI = 0.f, aA = 0.f, aB = 0.f;

    for (int h = r0; h < r0 + RB; ++h) {
        // per-lane segment sums of vr
        const float p1 = vr[0];
        const float p2 = p1 + vr[1];
        const float p3 = p2 + vr[2];
        const float p4 = p3 + vr[3];
        const float p5 = p4 + vr[4];
        const float p6 = p5 + vr[5];
        const float p7 = p6 + vr[6];
        const float s  = p7 + vr[7];
        const float f1 = s - p1, f2 = s - p2, f3 = s - p3, f4 = s - p4;
        const float f5 = s - p5, f6 = s - p6, f7 = s - p7;

        // cross-lane pieces (16 shuffles)
        const float sL1 = __shfl_up(s, 1, 64);
        const float sR1 = __shfl_down(s, 1, 64);
        const float g1 = __shfl_up(f1, 2, 64);
        const float g2 = __shfl_up(f2, 2, 64);
        const float g3 = __shfl_up(f3, 2, 64);
        const float g4 = __shfl_up(f4, 2, 64);
        const float g5 = __shfl_up(f5, 2, 64);
        const float g6 = __shfl_up(f6, 2, 64);
        const float g7 = __shfl_up(f7, 2, 64);
        const float q1 = __shfl_down(p1, 2, 64);
        const float q2 = __shfl_down(p2, 2, 64);
        const float q3 = __shfl_down(p3, 2, 64);
        const float q4 = __shfl_down(p4, 2, 64);
        const float q5 = __shfl_down(p5, 2, 64);
        const float q6 = __shfl_down(p6, 2, 64);
        const float q7 = __shfl_down(p7, 2, 64);

        const float S3 = fmaf(mL1, sL1, fmaf(mR1, sR1, s));
        float win[8];
        win[0] = fmaf(mL2, g1, S3);
        win[1] = fmaf(mL2, g2, fmaf(mR2, q1, S3));
        win[2] = fmaf(mL2, g3, fmaf(mR2, q2, S3));
        win[3] = fmaf(mL2, g4, fmaf(mR2, q3, S3));
        win[4] = fmaf(mL2, g5, fmaf(mR2, q4, S3));
        win[5] = fmaf(mL2, g6, fmaf(mR2, q5, S3));
        win[6] = fmaf(mL2, g7, fmaf(mR2, q6, S3));
        win[7] = fmaf(mR2, q7, S3);

        const float4 t0 = *(const float4*)(timg + (size_t)h * W + col0);
        const float4 t1 = *(const float4*)(timg + (size_t)h * W + col0 + 4);
        const float4 i0 = *(const float4*)(iimg + (size_t)h * W + col0);
        const float4 i1 = *(const float4*)(iimg + (size_t)h * W + col0 + 4);
        const float tv[8] = {t0.x, t0.y, t0.z, t0.w, t1.x, t1.y, t1.z, t1.w};
        const float iv[8] = {i0.x, i0.y, i0.z, i0.w, i1.x, i1.y, i1.z, i1.w};

        #pragma unroll
        for (int j = 0; j < 8; ++j) {
            const float wgt = fmaf(5.0f, fabsf(fmaf(win[j], inv, -tv[j])), 1.0f);
            aI += iv[j] * tv[j] * wgt;
            aA += iv[j] * wgt;
            aB += tv[j] * wgt;
        }

        // advance vertical window to row h+1: add h+16, sub h-15
        const int add = h + PADR + 1;
        const int sub = h - PADR;
        if (add < H) {
            const float4 a = *(const float4*)(timg + (size_t)add * W + col0);
            const float4 c = *(const float4*)(timg + (size_t)add * W + col0 + 4);
            vr[0] += a.x; vr[1] += a.y; vr[2] += a.z; vr[3] += a.w;
            vr[4] += c.x; vr[5] += c.y; vr[6] += c.z; vr[7] += c.w;
        }
        if (sub >= 0) {
            const float4 a = *(const float4*)(timg + (size_t)sub * W + col0);
            const float4 c = *(const float4*)(timg + (size_t)sub * W + col0 + 4);
            vr[0] -= a.x; vr[1] -= a.y; vr[2] -= a.z; vr[3] -= a.w;
            vr[4] -= c.x; vr[5] -= c.y; vr[6] -= c.z; vr[7] -= c.w;
        }
    }

    // wave reduction (64 lanes)
    #pragma unroll
    for (int off = 32; off > 0; off >>= 1) {
        aI += __shfl_down(aI, off, 64);
        aA += __shfl_down(aA, off, 64);
        aB += __shfl_down(aB, off, 64);
    }
    // block reduction across 4 waves; one uncontended float4 store per block
    __shared__ float part[3][4];
    if (lane == 0) { part[0][wv] = aI; part[1][wv] = aA; part[2][wv] = aB; }
    __syncthreads();
    if (tid == 0) {
        float4 o;
        o.x = part[0][0] + part[0][1] + part[0][2] + part[0][3];
        o.y = part[1][0] + part[1][1] + part[1][2] + part[1][3];
        o.z = part[2][0] + part[2][1] + part[2][2] + part[2][3];
        o.w = 0.f;
        partials[blockIdx.x] = o;
    }
}

// ---------------------------------------------------------------------------
// Reduce NBLK partials + finalize. One block, 1024 threads (16 waves).
// ---------------------------------------------------------------------------
__global__ __launch_bounds__(1024) void reduce_kernel(const float4* __restrict__ partials,
                                                      float* __restrict__ out) {
    const int tid = threadIdx.x;
    float aI = 0.f, aA = 0.f, aB = 0.f;
    for (int i = tid; i < NBLK; i += 1024) {
        const float4 v = partials[i];
        aI += v.x; aA += v.y; aB += v.z;
    }
    #pragma unroll
    for (int off = 32; off > 0; off >>= 1) {
        aI += __shfl_down(aI, off, 64);
        aA += __shfl_down(aA, off, 64);
        aB += __shfl_down(aB, off, 64);
    }
    __shared__ float s[3][16];
    const int wvx = tid >> 6, ln = tid & 63;
    if (ln == 0) { s[0][wvx] = aI; s[1][wvx] = aA; s[2][wvx] = aB; }
    __syncthreads();
    if (tid == 0) {
        float I = 0.f, A = 0.f, Bv = 0.f;
        #pragma unroll
        for (int k = 0; k < 16; ++k) { I += s[0][k]; A += s[1][k]; Bv += s[2][k]; }
        out[0] = 1.0f - (2.0f * I + 1.0f) / (A + Bv + 1.0f);
    }
}

extern "C" void kernel_launch(void* const* d_in, const int* in_sizes, int n_in,
                              void* d_out, int out_size, void* d_ws, size_t ws_size,
                              hipStream_t stream) {
    const float* inp = (const float*)d_in[0];   // "input"
    const float* tgt = (const float*)d_in[1];   // "target"
    float* out = (float*)d_out;

    // workspace: [0, NBLK*16) per-block partials (float4); written before read.
    float4* partials = (float4*)d_ws;

    fused_kernel<<<NBLK, 256, 0, stream>>>(tgt, inp, partials);
    reduce_kernel<<<1, 1024, 0, stream>>>(partials, out);
}

// Round 5
// 152.011 us; speedup vs baseline: 1.1515x; 1.1515x over previous
//
#include <hip/hip_runtime.h>

// WeightedDiceLoss on MI355X -- fused single-pass with LDS target-row ring.
// input, target: (64,1,512,512) fp32. Output: scalar fp32.
// weight = 1 + 5*|box31(target) - target|; loss = 1 - (2*I+1)/(A+B+1).
//
// Block (256 thr, 4 waves) owns a 64-row x 512-col band. LDS ring of 38 raw
// target rows; each target row is read from global ONCE per block (~1.47x
// total incl. halo), input once -> ~158 MB logical vs 330+ MB for the
// register-only variant (measured ~5 TB/s logical ceiling => ~40 us).
// Wave w handles rows R0+4j+w (stride-4 interleave keeps the live ring
// window <= 38 rows). Horizontal 31-window = R4's verified segment-sum +
// 16-shuffle construction, unchanged.

#define BATCH 64
#define H     512
#define W     512
#define PADR  15
#define RBAND 64                  // rows per block
#define RING  38                  // LDS ring rows (live span is exactly 38)
#define NBLK  (BATCH * (H / RBAND))   // 512 blocks

__global__ __launch_bounds__(256) void fused_kernel(const float* __restrict__ tgt,
                                                    const float* __restrict__ inp,
                                                    float4* __restrict__ partials) {
    const int tid  = threadIdx.x;
    const int lane = tid & 63;
    const int wv   = tid >> 6;
    const int blk  = blockIdx.x;
    const int band = blk & 7;                // H/RBAND = 8 bands
    const int b    = blk >> 3;
    const int R0   = band * RBAND;
    const float* timg = tgt + (size_t)b * H * W;
    const float* iimg = inp + (size_t)b * H * W;

    __shared__ __align__(16) float ring[RING * W];   // 77824 B -> 2 blocks/CU

    // ---- preload target rows R0-15 .. R0+22 (38 rows) into the ring -------
    // 38 rows x 128 float4 = 4864 units = 19 iterations x 256 threads.
    #pragma unroll
    for (int it = 0; it < 19; ++it) {
        const int u     = tid + it * 256;
        const int r_off = u >> 7;            // 0..37
        const int c4    = (u & 127) * 4;
        const int row   = R0 - 15 + r_off;
        float4 v = make_float4(0.f, 0.f, 0.f, 0.f);
        if (row >= 0 && row < H) v = *(const float4*)(timg + (size_t)row * W + c4);
        *(float4*)&ring[((row + RING) % RING) * W + c4] = v;
    }
    __syncthreads();

    // wave-edge masks for the horizontal window (zero padding)
    const float mL1 = (lane >= 1) ? 1.f : 0.f;
    const float mR1 = (lane <= 62) ? 1.f : 0.f;
    const float mL2 = (lane >= 2) ? 1.f : 0.f;
    const float mR2 = (lane <= 61) ? 1.f : 0.f;
    const int col0 = lane * 8;

    // ---- init vertical sums centered at row R0+wv (rows R0+wv-15..+15) ----
    float vr[8];
    #pragma unroll
    for (int k = 0; k < 8; ++k) vr[k] = 0.f;
    #pragma unroll
    for (int jj = -PADR; jj <= PADR; ++jj) {
        const int rr = R0 + wv + jj;                      // in [R0-15, R0+18]
        const int sl = ((rr + RING) % RING) * W + col0;
        const float4 a = *(const float4*)&ring[sl];
        const float4 c = *(const float4*)&ring[sl + 4];
        vr[0] += a.x; vr[1] += a.y; vr[2] += a.z; vr[3] += a.w;
        vr[4] += c.x; vr[5] += c.y; vr[6] += c.z; vr[7] += c.w;
    }

    const float inv = 1.0f / 961.0f;
    float aI = 0.f, aA = 0.f, aB = 0.f;

    for (int j = 0; j < 16; ++j) {
        const int h = R0 + 4 * j + wv;       // this wave's output row

        // prefetch (registers): next ring rows + this row's input, issued early
        float4 pf0 = make_float4(0.f, 0.f, 0.f, 0.f), pf1 = pf0;
        const int prow = R0 + 4 * j + 23 + wv;
        if (j < 14 && prow < H) {
            pf0 = *(const float4*)(timg + (size_t)prow * W + col0);
            pf1 = *(const float4*)(timg + (size_t)prow * W + col0 + 4);
        }
        const float4 i0 = *(const float4*)(iimg + (size_t)h * W + col0);
        const float4 i1 = *(const float4*)(iimg + (size_t)h * W + col0 + 4);

        // ---- horizontal window from current vr (R4 verified math) ----------
        const float p1 = vr[0];
        const float p2 = p1 + vr[1];
        const float p3 = p2 + vr[2];
        const float p4 = p3 + vr[3];
        const float p5 = p4 + vr[4];
        const float p6 = p5 + vr[5];
        const float p7 = p6 + vr[6];
        const float s  = p7 + vr[7];
        const float f1 = s - p1, f2 = s - p2, f3 = s - p3, f4 = s - p4;
        const float f5 = s - p5, f6 = s - p6, f7 = s - p7;

        const float sL1 = __shfl_up(s, 1, 64);
        const float sR1 = __shfl_down(s, 1, 64);
        const float g1 = __shfl_up(f1, 2, 64);
        const float g2 = __shfl_up(f2, 2, 64);
        const float g3 = __shfl_up(f3, 2, 64);
        const float g4 = __shfl_up(f4, 2, 64);
        const float g5 = __shfl_up(f5, 2, 64);
        const float g6 = __shfl_up(f6, 2, 64);
        const float g7 = __shfl_up(f7, 2, 64);
        const float q1 = __shfl_down(p1, 2, 64);
        const float q2 = __shfl_down(p2, 2, 64);
        const float q3 = __shfl_down(p3, 2, 64);
        const float q4 = __shfl_down(p4, 2, 64);
        const float q5 = __shfl_down(p5, 2, 64);
        const float q6 = __shfl_down(p6, 2, 64);
        const float q7 = __shfl_down(p7, 2, 64);

        const float S3 = fmaf(mL1, sL1, fmaf(mR1, sR1, s));
        float win[8];
        win[0] = fmaf(mL2, g1, S3);
        win[1] = fmaf(mL2, g2, fmaf(mR2, q1, S3));
        win[2] = fmaf(mL2, g3, fmaf(mR2, q2, S3));
        win[3] = fmaf(mL2, g4, fmaf(mR2, q3, S3));
        win[4] = fmaf(mL2, g5, fmaf(mR2, q4, S3));
        win[5] = fmaf(mL2, g6, fmaf(mR2, q5, S3));
        win[6] = fmaf(mL2, g7, fmaf(mR2, q6, S3));
        win[7] = fmaf(mR2, q7, S3);

        // center target row from the ring
        const int slC = (h % RING) * W + col0;
        const float4 t0 = *(const float4*)&ring[slC];
        const float4 t1 = *(const float4*)&ring[slC + 4];
        const float tv[8] = {t0.x, t0.y, t0.z, t0.w, t1.x, t1.y, t1.z, t1.w};
        const float iv[8] = {i0.x, i0.y, i0.z, i0.w, i1.x, i1.y, i1.z, i1.w};

        #pragma unroll
        for (int k = 0; k < 8; ++k) {
            const float wgt = fmaf(5.0f, fabsf(fmaf(win[k], inv, -tv[k])), 1.0f);
            aI += iv[k] * tv[k] * wgt;
            aA += iv[k] * wgt;
            aB += tv[k] * wgt;
        }

        // ---- advance vr by 4 rows: +rows h+16..h+19, -rows h-15..h-12 ------
        if (j < 15) {
            #pragma unroll
            for (int q = 0; q < 4; ++q) {
                const int slA = ((h + 16 + q) % RING) * W + col0;         // >=16
                const int slS = (((h - 15 + q) + RING) % RING) * W + col0; // >=-15
                const float4 a0 = *(const float4*)&ring[slA];
                const float4 a1 = *(const float4*)&ring[slA + 4];
                const float4 s0 = *(const float4*)&ring[slS];
                const float4 s1 = *(const float4*)&ring[slS + 4];
                vr[0] += a0.x - s0.x; vr[1] += a0.y - s0.y;
                vr[2] += a0.z - s0.z; vr[3] += a0.w - s0.w;
                vr[4] += a1.x - s1.x; vr[5] += a1.y - s1.y;
                vr[6] += a1.z - s1.z; vr[7] += a1.w - s1.w;
            }
        }
        __syncthreads();

        // ---- publish prefetched rows R0+4j+23..26 into the ring ------------
        if (j < 14) {
            const int sl = (prow % RING) * W + col0;      // prow >= 23
            *(float4*)&ring[sl]     = pf0;
            *(float4*)&ring[sl + 4] = pf1;
        }
        __syncthreads();
    }

    // wave reduction (64 lanes)
    #pragma unroll
    for (int off = 32; off > 0; off >>= 1) {
        aI += __shfl_down(aI, off, 64);
        aA += __shfl_down(aA, off, 64);
        aB += __shfl_down(aB, off, 64);
    }
    // cross-wave reduction reusing ring storage (no extra LDS)
    if (lane == 0) { ring[wv] = aI; ring[8 + wv] = aA; ring[16 + wv] = aB; }
    __syncthreads();
    if (tid == 0) {
        float4 o;
        o.x = ring[0] + ring[1] + ring[2] + ring[3];
        o.y = ring[8] + ring[9] + ring[10] + ring[11];
        o.z = ring[16] + ring[17] + ring[18] + ring[19];
        o.w = 0.f;
        partials[blk] = o;
    }
}

// ---------------------------------------------------------------------------
// Reduce NBLK (512) partials + finalize. One block, 512 threads (8 waves).
// ---------------------------------------------------------------------------
__global__ __launch_bounds__(512) void reduce_kernel(const float4* __restrict__ partials,
                                                     float* __restrict__ out) {
    const int tid = threadIdx.x;
    const float4 v = partials[tid];          // exactly 512 entries
    float aI = v.x, aA = v.y, aB = v.z;
    #pragma unroll
    for (int off = 32; off > 0; off >>= 1) {
        aI += __shfl_down(aI, off, 64);
        aA += __shfl_down(aA, off, 64);
        aB += __shfl_down(aB, off, 64);
    }
    __shared__ float s[3][8];
    const int wvx = tid >> 6, ln = tid & 63;
    if (ln == 0) { s[0][wvx] = aI; s[1][wvx] = aA; s[2][wvx] = aB; }
    __syncthreads();
    if (tid == 0) {
        float I = 0.f, A = 0.f, Bv = 0.f;
        #pragma unroll
        for (int k = 0; k < 8; ++k) { I += s[0][k]; A += s[1][k]; Bv += s[2][k]; }
        out[0] = 1.0f - (2.0f * I + 1.0f) / (A + Bv + 1.0f);
    }
}

extern "C" void kernel_launch(void* const* d_in, const int* in_sizes, int n_in,
                              void* d_out, int out_size, void* d_ws, size_t ws_size,
                              hipStream_t stream) {
    const float* inp = (const float*)d_in[0];   // "input"
    const float* tgt = (const float*)d_in[1];   // "target"
    float* out = (float*)d_out;

    // workspace: [0, NBLK*16) per-block partials (float4); written before read.
    float4* partials = (float4*)d_ws;

    fused_kernel<<<NBLK, 256, 0, stream>>>(tgt, inp, partials);
    reduce_kernel<<<1, 512, 0, stream>>>(partials, out);
}

// Round 6
// 150.221 us; speedup vs baseline: 1.1652x; 1.0119x over previous
//
#include <hip/hip_runtime.h>

// WeightedDiceLoss on MI355X -- fused single-pass, LDS row-ring, round 6:
// de-interleaved conflict-free ring layout + early-issued loads.
// input, target: (64,1,512,512) fp32. Output: scalar fp32.
// weight = 1 + 5*|box31(target) - target|; loss = 1 - (2*I+1)/(A+B+1).
//
// Ring layout (per row slot, 512 floats): even float4-units (cols 8i..8i+3)
// at dword offset lane*4, odd units (cols 8i+4..8i+7) at 256 + lane*4.
// Every wave access is lane-stride-4-dword contiguous => 0 bank conflicts
// (R5 measured 3.19M conflicts with the col0=lane*8 direct layout).

#define BATCH 64
#define H     512
#define W     512
#define PADR  15
#define RBAND 64                  // rows per block
#define RING  38                  // ring rows (live span exactly 38)
#define NBLK  (BATCH * (H / RBAND))   // 512 blocks

__global__ __launch_bounds__(256) void fused_kernel(const float* __restrict__ tgt,
                                                    const float* __restrict__ inp,
                                                    float4* __restrict__ partials) {
    const int tid  = threadIdx.x;
    const int lane = tid & 63;
    const int wv   = tid >> 6;
    const int blk  = blockIdx.x;
    const int band = blk & 7;                // H/RBAND = 8 bands
    const int b    = blk >> 3;
    const int R0   = band * RBAND;
    const float* timg = tgt + (size_t)b * H * W;
    const float* iimg = inp + (size_t)b * H * W;

    __shared__ __align__(16) float ring[RING * W];   // 77824 B -> 2 blocks/CU

    const int col0 = lane * 8;               // this lane's 8 columns
    const int ofsE = lane * 4;               // ring dword ofs, even half
    const int ofsO = 256 + lane * 4;         // ring dword ofs, odd half

    // ---- preload target rows R0-15 .. R0+22 (38 rows), publish-style ------
    // wave wv handles r_off = wv, wv+4, ... (conflict-free writes)
    for (int k = 0; k < 10; ++k) {
        const int r_off = wv + 4 * k;
        if (r_off < RING) {
            const int row = R0 - 15 + r_off;
            float4 v0 = make_float4(0.f, 0.f, 0.f, 0.f), v1 = v0;
            if (row >= 0 && row < H) {
                v0 = *(const float4*)(timg + (size_t)row * W + col0);
                v1 = *(const float4*)(timg + (size_t)row * W + col0 + 4);
            }
            const int slot = (row + RING) % RING;
            *(float4*)&ring[slot * W + ofsE] = v0;
            *(float4*)&ring[slot * W + ofsO] = v1;
        }
    }
    __syncthreads();

    // wave-edge masks for the horizontal window (zero padding)
    const float mL1 = (lane >= 1) ? 1.f : 0.f;
    const float mR1 = (lane <= 62) ? 1.f : 0.f;
    const float mL2 = (lane >= 2) ? 1.f : 0.f;
    const float mR2 = (lane <= 61) ? 1.f : 0.f;

    // ---- init vertical sums centered at row R0+wv (rows R0+wv-15..+15) ----
    float vr[8];
    #pragma unroll
    for (int k = 0; k < 8; ++k) vr[k] = 0.f;
    #pragma unroll
    for (int jj = -PADR; jj <= PADR; ++jj) {
        const int rr = R0 + wv + jj;                      // in [R0-15, R0+18]
        const int sl = ((rr + RING) % RING) * W;
        const float4 a = *(const float4*)&ring[sl + ofsE];
        const float4 c = *(const float4*)&ring[sl + ofsO];
        vr[0] += a.x; vr[1] += a.y; vr[2] += a.z; vr[3] += a.w;
        vr[4] += c.x; vr[5] += c.y; vr[6] += c.z; vr[7] += c.w;
    }

    const float inv = 1.0f / 961.0f;
    float aI = 0.f, aA = 0.f, aB = 0.f;

    for (int j = 0; j < 16; ++j) {
        const int h = R0 + 4 * j + wv;       // this wave's output row

        // ---- issue ALL loads for this step up front (overlap with VALU) ----
        // global: prefetch ring rows (consumed from step j+1) + this row input
        float4 pf0 = make_float4(0.f, 0.f, 0.f, 0.f), pf1 = pf0;
        const int prow = R0 + 4 * j + 23 + wv;
        if (j < 14 && prow < H) {
            pf0 = *(const float4*)(timg + (size_t)prow * W + col0);
            pf1 = *(const float4*)(timg + (size_t)prow * W + col0 + 4);
        }
        const float4 i0 = *(const float4*)(iimg + (size_t)h * W + col0);
        const float4 i1 = *(const float4*)(iimg + (size_t)h * W + col0 + 4);

        // LDS: center target row
        const int slC = (h % RING) * W;
        const float4 t0 = *(const float4*)&ring[slC + ofsE];
        const float4 t1 = *(const float4*)&ring[slC + ofsO];

        // LDS: vr-advance rows (+16..+19, -15..-12), into temps, applied later
        float4 adv0[4], adv1[4], sb0[4], sb1[4];
        if (j < 15) {
            #pragma unroll
            for (int q = 0; q < 4; ++q) {
                const int slA = ((h + 16 + q) % RING) * W;
                const int slS = (((h - 15 + q) + RING) % RING) * W;
                adv0[q] = *(const float4*)&ring[slA + ofsE];
                adv1[q] = *(const float4*)&ring[slA + ofsO];
                sb0[q]  = *(const float4*)&ring[slS + ofsE];
                sb1[q]  = *(const float4*)&ring[slS + ofsO];
            }
        }

        // ---- horizontal window from current vr (verified segment-sum) -----
        const float p1 = vr[0];
        const float p2 = p1 + vr[1];
        const float p3 = p2 + vr[2];
        const float p4 = p3 + vr[3];
        const float p5 = p4 + vr[4];
        const float p6 = p5 + vr[5];
        const float p7 = p6 + vr[6];
        const float s  = p7 + vr[7];
        const float f1 = s - p1, f2 = s - p2, f3 = s - p3, f4 = s - p4;
        const float f5 = s - p5, f6 = s - p6, f7 = s - p7;

        const float sL1 = __shfl_up(s, 1, 64);
        const float sR1 = __shfl_down(s, 1, 64);
        const float g1 = __shfl_up(f1, 2, 64);
        const float g2 = __shfl_up(f2, 2, 64);
        const float g3 = __shfl_up(f3, 2, 64);
        const float g4 = __shfl_up(f4, 2, 64);
        const float g5 = __shfl_up(f5, 2, 64);
        const float g6 = __shfl_up(f6, 2, 64);
        const float g7 = __shfl_up(f7, 2, 64);
        const float q1 = __shfl_down(p1, 2, 64);
        const float q2 = __shfl_down(p2, 2, 64);
        const float q3 = __shfl_down(p3, 2, 64);
        const float q4 = __shfl_down(p4, 2, 64);
        const float q5 = __shfl_down(p5, 2, 64);
        const float q6 = __shfl_down(p6, 2, 64);
        const float q7 = __shfl_down(p7, 2, 64);

        const float S3 = fmaf(mL1, sL1, fmaf(mR1, sR1, s));
        float win[8];
        win[0] = fmaf(mL2, g1, S3);
        win[1] = fmaf(mL2, g2, fmaf(mR2, q1, S3));
        win[2] = fmaf(mL2, g3, fmaf(mR2, q2, S3));
        win[3] = fmaf(mL2, g4, fmaf(mR2, q3, S3));
        win[4] = fmaf(mL2, g5, fmaf(mR2, q4, S3));
        win[5] = fmaf(mL2, g6, fmaf(mR2, q5, S3));
        win[6] = fmaf(mL2, g7, fmaf(mR2, q6, S3));
        win[7] = fmaf(mR2, q7, S3);

        const float tv[8] = {t0.x, t0.y, t0.z, t0.w, t1.x, t1.y, t1.z, t1.w};
        const float iv[8] = {i0.x, i0.y, i0.z, i0.w, i1.x, i1.y, i1.z, i1.w};

        #pragma unroll
        for (int k = 0; k < 8; ++k) {
            const float wgt = fmaf(5.0f, fabsf(fmaf(win[k], inv, -tv[k])), 1.0f);
            aI += iv[k] * tv[k] * wgt;
            aA += iv[k] * wgt;
            aB += tv[k] * wgt;
        }

        // ---- apply vr advance from temps ----------------------------------
        if (j < 15) {
            #pragma unroll
            for (int q = 0; q < 4; ++q) {
                vr[0] += adv0[q].x - sb0[q].x; vr[1] += adv0[q].y - sb0[q].y;
                vr[2] += adv0[q].z - sb0[q].z; vr[3] += adv0[q].w - sb0[q].w;
                vr[4] += adv1[q].x - sb1[q].x; vr[5] += adv1[q].y - sb1[q].y;
                vr[6] += adv1[q].z - sb1[q].z; vr[7] += adv1[q].w - sb1[q].w;
            }
        }
        __syncthreads();

        // ---- publish prefetched rows R0+4j+23..26 into the ring -----------
        if (j < 14) {
            const int sl = (prow % RING) * W;      // prow >= 23
            *(float4*)&ring[sl + ofsE] = pf0;
            *(float4*)&ring[sl + ofsO] = pf1;
        }
        __syncthreads();
    }

    // wave reduction (64 lanes)
    #pragma unroll
    for (int off = 32; off > 0; off >>= 1) {
        aI += __shfl_down(aI, off, 64);
        aA += __shfl_down(aA, off, 64);
        aB += __shfl_down(aB, off, 64);
    }
    // cross-wave reduction reusing ring storage
    if (lane == 0) { ring[wv] = aI; ring[8 + wv] = aA; ring[16 + wv] = aB; }
    __syncthreads();
    if (tid == 0) {
        float4 o;
        o.x = ring[0] + ring[1] + ring[2] + ring[3];
        o.y = ring[8] + ring[9] + ring[10] + ring[11];
        o.z = ring[16] + ring[17] + ring[18] + ring[19];
        o.w = 0.f;
        partials[blk] = o;
    }
}

// ---------------------------------------------------------------------------
// Reduce NBLK (512) partials + finalize. One block, 512 threads (8 waves).
// ---------------------------------------------------------------------------
__global__ __launch_bounds__(512) void reduce_kernel(const float4* __restrict__ partials,
                                                     float* __restrict__ out) {
    const int tid = threadIdx.x;
    const float4 v = partials[tid];          // exactly 512 entries
    float aI = v.x, aA = v.y, aB = v.z;
    #pragma unroll
    for (int off = 32; off > 0; off >>= 1) {
        aI += __shfl_down(aI, off, 64);
        aA += __shfl_down(aA, off, 64);
        aB += __shfl_down(aB, off, 64);
    }
    __shared__ float s[3][8];
    const int wvx = tid >> 6, ln = tid & 63;
    if (ln == 0) { s[0][wvx] = aI; s[1][wvx] = aA; s[2][wvx] = aB; }
    __syncthreads();
    if (tid == 0) {
        float I = 0.f, A = 0.f, Bv = 0.f;
        #pragma unroll
        for (int k = 0; k < 8; ++k) { I += s[0][k]; A += s[1][k]; Bv += s[2][k]; }
        out[0] = 1.0f - (2.0f * I + 1.0f) / (A + Bv + 1.0f);
    }
}

extern "C" void kernel_launch(void* const* d_in, const int* in_sizes, int n_in,
                              void* d_out, int out_size, void* d_ws, size_t ws_size,
                              hipStream_t stream) {
    const float* inp = (const float*)d_in[0];   // "input"
    const float* tgt = (const float*)d_in[1];   // "target"
    float* out = (float*)d_out;

    // workspace: [0, NBLK*16) per-block partials (float4); written before read.
    float4* partials = (float4*)d_ws;

    fused_kernel<<<NBLK, 256, 0, stream>>>(tgt, inp, partials);
    reduce_kernel<<<1, 512, 0, stream>>>(partials, out);
}

// Round 7
// 148.156 us; speedup vs baseline: 1.1814x; 1.0139x over previous
//
#include <hip/hip_runtime.h>
#include <hip/hip_bf16.h>

// WeightedDiceLoss on MI355X -- fused single-pass, bf16 LDS row-ring, round 7:
// ring stored as packed bf16 (halves LDS -> 38KB -> 4 blocks/CU), RBAND=32
// (1024 blocks so the grid can actually fill 4 blocks/CU = 16 waves/CU), and
// r<H guard on add-rows (fixes latent stale-slot read in R5/R6 last band).
// input, target: (64,1,512,512) fp32. Output: scalar fp32.
// weight = 1 + 5*|box31(target) - target|; loss = 1 - (2*I+1)/(A+B+1).
//
// Ring layout: row slot = 256 u32; u32 d holds cols (2d, 2d+1) as bf16
// (low 16 = even col). Lane reads its 8 cols as ONE uint4 at dword 4*lane
// -> lane-stride-4-dword contiguous, conflict-free (R6-verified pattern).

#define BATCH 64
#define H     512
#define W     512
#define PADR  15
#define RBAND 32                  // rows per block
#define RING  38                  // ring rows (live span exactly 38)
#define NBLK  (BATCH * (H / RBAND))   // 1024 blocks

static __device__ __forceinline__ unsigned pack2(float e, float o) {
    __hip_bfloat162 h = __float22bfloat162_rn(make_float2(e, o));
    unsigned u; __builtin_memcpy(&u, &h, 4); return u;
}
static __device__ __forceinline__ float2 unpk(unsigned u) {
    return make_float2(__uint_as_float(u << 16),
                       __uint_as_float(u & 0xffff0000u));
}

__global__ __launch_bounds__(256, 4) void fused_kernel(const float* __restrict__ tgt,
                                                       const float* __restrict__ inp,
                                                       float4* __restrict__ partials) {
    const int tid  = threadIdx.x;
    const int lane = tid & 63;
    const int wv   = tid >> 6;
    const int blk  = blockIdx.x;
    const int band = blk & 15;               // H/RBAND = 16 bands
    const int b    = blk >> 4;
    const int R0   = band * RBAND;
    const float* timg = tgt + (size_t)b * H * W;
    const float* iimg = inp + (size_t)b * H * W;

    __shared__ __align__(16) unsigned ring[RING * 256];   // 38912 B -> 4 blocks/CU

    const int col0 = lane * 8;               // this lane's 8 columns
    const int ofs  = lane * 4;               // lane's uint4 dword offset in a slot

    // ---- preload target rows R0-15 .. R0+22 (38 rows), pack to bf16 -------
    for (int k = 0; k < 10; ++k) {
        const int r_off = wv + 4 * k;
        if (r_off < RING) {
            const int row = R0 - 15 + r_off;  // max R0+22 <= 502 < H always
            float4 v0 = make_float4(0.f, 0.f, 0.f, 0.f), v1 = v0;
            if (row >= 0) {
                v0 = *(const float4*)(timg + (size_t)row * W + col0);
                v1 = *(const float4*)(timg + (size_t)row * W + col0 + 4);
            }
            uint4 u;
            u.x = pack2(v0.x, v0.y); u.y = pack2(v0.z, v0.w);
            u.z = pack2(v1.x, v1.y); u.w = pack2(v1.z, v1.w);
            *(uint4*)&ring[((row + RING) % RING) * 256 + ofs] = u;
        }
    }
    __syncthreads();

    // wave-edge masks for the horizontal window (zero padding)
    const float mL1 = (lane >= 1) ? 1.f : 0.f;
    const float mR1 = (lane <= 62) ? 1.f : 0.f;
    const float mL2 = (lane >= 2) ? 1.f : 0.f;
    const float mR2 = (lane <= 61) ? 1.f : 0.f;

    // ---- init vertical sums centered at row R0+wv (rows R0+wv-15..+15) ----
    float vr[8];
    #pragma unroll
    for (int k = 0; k < 8; ++k) vr[k] = 0.f;
    #pragma unroll
    for (int jj = -PADR; jj <= PADR; ++jj) {
        const int rr = R0 + wv + jj;                      // in [R0-15, R0+18]
        const uint4 c = *(const uint4*)&ring[((rr + RING) % RING) * 256 + ofs];
        const float2 e0 = unpk(c.x), e1 = unpk(c.y), e2 = unpk(c.z), e3 = unpk(c.w);
        vr[0] += e0.x; vr[1] += e0.y; vr[2] += e1.x; vr[3] += e1.y;
        vr[4] += e2.x; vr[5] += e2.y; vr[6] += e3.x; vr[7] += e3.y;
    }

    const float inv = 1.0f / 961.0f;
    float aI = 0.f, aA = 0.f, aB = 0.f;

    for (int j = 0; j < 8; ++j) {
        const int h = R0 + 4 * j + wv;       // this wave's output row

        // ---- issue ALL loads for this step up front (overlap with VALU) ----
        float4 pf0 = make_float4(0.f, 0.f, 0.f, 0.f), pf1 = pf0;
        const int prow = R0 + 4 * j + 23 + wv;
        if (j < 7 && prow < H) {
            pf0 = *(const float4*)(timg + (size_t)prow * W + col0);
            pf1 = *(const float4*)(timg + (size_t)prow * W + col0 + 4);
        }
        const float4 i0 = *(const float4*)(iimg + (size_t)h * W + col0);
        const float4 i1 = *(const float4*)(iimg + (size_t)h * W + col0 + 4);

        // LDS: center target row (bf16)
        const uint4 tc = *(const uint4*)&ring[(h % RING) * 256 + ofs];

        // LDS: vr-advance rows (+16..+19 guarded r<H, -15..-12), into temps
        uint4 ua[4], us[4];
        if (j < 7) {
            #pragma unroll
            for (int q = 0; q < 4; ++q) {
                const int ar = h + 16 + q;
                ua[q] = (ar < H) ? *(const uint4*)&ring[(ar % RING) * 256 + ofs]
                                 : make_uint4(0u, 0u, 0u, 0u);
                us[q] = *(const uint4*)&ring[(((h - 15 + q) + RING) % RING) * 256 + ofs];
            }
        }

        // ---- horizontal window from current vr (verified segment-sum) -----
        const float p1 = vr[0];
        const float p2 = p1 + vr[1];
        const float p3 = p2 + vr[2];
        const float p4 = p3 + vr[3];
        const float p5 = p4 + vr[4];
        const float p6 = p5 + vr[5];
        const float p7 = p6 + vr[6];
        const float s  = p7 + vr[7];
        const float f1 = s - p1, f2 = s - p2, f3 = s - p3, f4 = s - p4;
        const float f5 = s - p5, f6 = s - p6, f7 = s - p7;

        const float sL1 = __shfl_up(s, 1, 64);
        const float sR1 = __shfl_down(s, 1, 64);
        const float g1 = __shfl_up(f1, 2, 64);
        const float g2 = __shfl_up(f2, 2, 64);
        const float g3 = __shfl_up(f3, 2, 64);
        const float g4 = __shfl_up(f4, 2, 64);
        const float g5 = __shfl_up(f5, 2, 64);
        const float g6 = __shfl_up(f6, 2, 64);
        const float g7 = __shfl_up(f7, 2, 64);
        const float q1 = __shfl_down(p1, 2, 64);
        const float q2 = __shfl_down(p2, 2, 64);
        const float q3 = __shfl_down(p3, 2, 64);
        const float q4 = __shfl_down(p4, 2, 64);
        const float q5 = __shfl_down(p5, 2, 64);
        const float q6 = __shfl_down(p6, 2, 64);
        const float q7 = __shfl_down(p7, 2, 64);

        const float S3 = fmaf(mL1, sL1, fmaf(mR1, sR1, s));
        float win[8];
        win[0] = fmaf(mL2, g1, S3);
        win[1] = fmaf(mL2, g2, fmaf(mR2, q1, S3));
        win[2] = fmaf(mL2, g3, fmaf(mR2, q2, S3));
        win[3] = fmaf(mL2, g4, fmaf(mR2, q3, S3));
        win[4] = fmaf(mL2, g5, fmaf(mR2, q4, S3));
        win[5] = fmaf(mL2, g6, fmaf(mR2, q5, S3));
        win[6] = fmaf(mL2, g7, fmaf(mR2, q6, S3));
        win[7] = fmaf(mR2, q7, S3);

        const float2 t0 = unpk(tc.x), t1 = unpk(tc.y), t2 = unpk(tc.z), t3 = unpk(tc.w);
        const float tv[8] = {t0.x, t0.y, t1.x, t1.y, t2.x, t2.y, t3.x, t3.y};
        const float iv[8] = {i0.x, i0.y, i0.z, i0.w, i1.x, i1.y, i1.z, i1.w};

        #pragma unroll
        for (int k = 0; k < 8; ++k) {
            const float wgt = fmaf(5.0f, fabsf(fmaf(win[k], inv, -tv[k])), 1.0f);
            aI += iv[k] * tv[k] * wgt;
            aA += iv[k] * wgt;
            aB += tv[k] * wgt;
        }

        // ---- apply vr advance from temps ----------------------------------
        if (j < 7) {
            #pragma unroll
            for (int q = 0; q < 4; ++q) {
                const float2 a0 = unpk(ua[q].x), a1 = unpk(ua[q].y),
                             a2 = unpk(ua[q].z), a3 = unpk(ua[q].w);
                const float2 s0 = unpk(us[q].x), s1 = unpk(us[q].y),
                             s2 = unpk(us[q].z), s3 = unpk(us[q].w);
                vr[0] += a0.x - s0.x; vr[1] += a0.y - s0.y;
                vr[2] += a1.x - s1.x; vr[3] += a1.y - s1.y;
                vr[4] += a2.x - s2.x; vr[5] += a2.y - s2.y;
                vr[6] += a3.x - s3.x; vr[7] += a3.y - s3.y;
            }
        }
        __syncthreads();

        // ---- publish prefetched rows R0+4j+23..26 into the ring -----------
        if (j < 7 && prow < H) {
            uint4 u;
            u.x = pack2(pf0.x, pf0.y); u.y = pack2(pf0.z, pf0.w);
            u.z = pack2(pf1.x, pf1.y); u.w = pack2(pf1.z, pf1.w);
            *(uint4*)&ring[(prow % RING) * 256 + ofs] = u;
        }
        __syncthreads();
    }

    // wave reduction (64 lanes)
    #pragma unroll
    for (int off = 32; off > 0; off >>= 1) {
        aI += __shfl_down(aI, off, 64);
        aA += __shfl_down(aA, off, 64);
        aB += __shfl_down(aB, off, 64);
    }
    // cross-wave reduction reusing ring storage
    float* rf = (float*)ring;
    if (lane == 0) { rf[wv] = aI; rf[8 + wv] = aA; rf[16 + wv] = aB; }
    __syncthreads();
    if (tid == 0) {
        float4 o;
        o.x = rf[0] + rf[1] + rf[2] + rf[3];
        o.y = rf[8] + rf[9] + rf[10] + rf[11];
        o.z = rf[16] + rf[17] + rf[18] + rf[19];
        o.w = 0.f;
        partials[blk] = o;
    }
}

// ---------------------------------------------------------------------------
// Reduce NBLK (1024) partials + finalize. One block, 1024 threads (16 waves).
// ---------------------------------------------------------------------------
__global__ __launch_bounds__(1024) void reduce_kernel(const float4* __restrict__ partials,
                                                      float* __restrict__ out) {
    const int tid = threadIdx.x;
    const float4 v = partials[tid];          // exactly 1024 entries
    float aI = v.x, aA = v.y, aB = v.z;
    #pragma unroll
    for (int off = 32; off > 0; off >>= 1) {
        aI += __shfl_down(aI, off, 64);
        aA += __shfl_down(aA, off, 64);
        aB += __shfl_down(aB, off, 64);
    }
    __shared__ float s[3][16];
    const int wvx = tid >> 6, ln = tid & 63;
    if (ln == 0) { s[0][wvx] = aI; s[1][wvx] = aA; s[2][wvx] = aB; }
    __syncthreads();
    if (tid == 0) {
        float I = 0.f, A = 0.f, Bv = 0.f;
        #pragma unroll
        for (int k = 0; k < 16; ++k) { I += s[0][k]; A += s[1][k]; Bv += s[2][k]; }
        out[0] = 1.0f - (2.0f * I + 1.0f) / (A + Bv + 1.0f);
    }
}

extern "C" void kernel_launch(void* const* d_in, const int* in_sizes, int n_in,
                              void* d_out, int out_size, void* d_ws, size_t ws_size,
                              hipStream_t stream) {
    const float* inp = (const float*)d_in[0];   // "input"
    const float* tgt = (const float*)d_in[1];   // "target"
    float* out = (float*)d_out;

    // workspace: [0, NBLK*16) per-block partials (float4); written before read.
    float4* partials = (float4*)d_ws;

    fused_kernel<<<NBLK, 256, 0, stream>>>(tgt, inp, partials);
    reduce_kernel<<<1, 1024, 0, stream>>>(partials, out);
}